// Round 4
// baseline (458.724 us; speedup 1.0000x reference)
//
#include <hip/hip_runtime.h>
#include <hip/hip_bf16.h>
#include <cstdint>

static constexpr int MROWS = 147456;
static constexpr int KDIM  = 256;

typedef __bf16 bf16x8 __attribute__((ext_vector_type(8)));
typedef float  f32x4  __attribute__((ext_vector_type(4)));

static __device__ __forceinline__ uint16_t f2bf(float f) {
    uint32_t x = __float_as_uint(f);
    x += 0x7FFFu + ((x >> 16) & 1u);   // RNE
    return (uint16_t)(x >> 16);
}
static __device__ __forceinline__ uint32_t pack2(float a, float b) {
    return (uint32_t)f2bf(a) | ((uint32_t)f2bf(b) << 16);
}

// ============================================================
// Weight pre-gather: Wb[hb][t][j][kk] = bf16(W_qkv[t*32+kk][gcol(hb,j)])
// j in [0,384): 0-127 q(4 heads), 128-255 k, 256-383 v for half hb.
// ============================================================
static __device__ __forceinline__ int gcol(int hb, int j) {
    if (j < 128) return hb * 128 + j;
    if (j < 256) return 256 + hb * 128 + (j - 128);
    return 512 + hb * 128 + (j - 256);
}

__global__ void build_wb(const float* __restrict__ Wqkv, uint16_t* __restrict__ Wb)
{
    int id = blockIdx.x * blockDim.x + threadIdx.x;
    if (id >= 2 * 8 * 384 * 32) return;
    int kk = id & 31;
    int tmp = id >> 5;            // (hb*8+t)*384 + j
    int j = tmp % 384;
    int ht = tmp / 384;
    int t = ht & 7, hb = ht >> 3;
    int k = t * 32 + kk;
    Wb[id] = f2bf(Wqkv[(size_t)k * 768 + gcol(hb, j)]);
}

__global__ void build_biasb(const float* __restrict__ bq, float* __restrict__ biasb)
{
    int id = blockIdx.x * blockDim.x + threadIdx.x;
    if (id >= 768) return;
    int hb = id / 384, j = id % 384;
    biasb[id] = bq[gcol(hb, j)];
}

// Wt[n][k] = bf16(W[k][n])
__global__ void transpose_cvt_k(const float* __restrict__ W, uint16_t* __restrict__ Wt, int K, int N)
{
    int id = blockIdx.x * blockDim.x + threadIdx.x;
    if (id >= K * N) return;
    int n = id / K, k = id - n * K;
    Wt[id] = f2bf(W[(size_t)k * N + n]);
}

// ============================================================
// bf16 MFMA GEMM (proj): C[M,N] = A[M,K] @ Bt[N,K]^T + bias
// ============================================================
template<int OUT_BF16>
__global__ __launch_bounds__(256)
void gemm_bf16(const uint16_t* __restrict__ A, const uint16_t* __restrict__ Bt,
               const float* __restrict__ bias, void* __restrict__ Cout,
               int M, int N, int K, int ntn)
{
    __shared__ __align__(16) uint16_t lds[2][2][128 * 32];

    const int tid = threadIdx.x;
    const int wv = tid >> 6, ln = tid & 63;

    const int nwg = gridDim.x;
    const int q8 = nwg >> 3;
    const int sw = (blockIdx.x & 7) * q8 + (blockIdx.x >> 3);
    const int bm = (sw / ntn) * 128;
    const int bn = (sw - (sw / ntn) * ntn) * 128;

    const uint16_t* Ab = A + (size_t)bm * K;
    const uint16_t* Bb = Bt + (size_t)bn * K;

    const int wr = (wv >> 1) * 64;
    const int wc = (wv & 1) * 64;
    const int frow = ln & 15;
    const int kb = (ln >> 4) * 16;

    f32x4 acc[4][4] = {};

    auto stage = [&](int buf, int k0) {
        #pragma unroll
        for (int it = 0; it < 2; ++it) {
            const int c = it * 256 + wv * 64 + ln;
            const int row = c >> 2, kl = c & 3;
            const int ks = kl ^ ((row ^ (row >> 2)) & 3);
            const uint16_t* srcA = Ab + row * K + k0 + ks * 8;
            const uint16_t* srcB = Bb + row * K + k0 + ks * 8;
            uint16_t* dA = &lds[buf][0][(size_t)(it * 256 + wv * 64) * 8];
            uint16_t* dB = &lds[buf][1][(size_t)(it * 256 + wv * 64) * 8];
            __builtin_amdgcn_global_load_lds((const __attribute__((address_space(1))) void*)srcA,
                                             (__attribute__((address_space(3))) void*)dA, 16, 0, 0);
            __builtin_amdgcn_global_load_lds((const __attribute__((address_space(1))) void*)srcB,
                                             (__attribute__((address_space(3))) void*)dB, 16, 0, 0);
        }
    };

    stage(0, 0);
    const int nt = K / 32;
    for (int t = 0; t < nt; ++t) {
        const int cur = t & 1;
        __syncthreads();
        if (t + 1 < nt) stage(cur ^ 1, (t + 1) * 32);
        bf16x8 af[4], bfr[4];
        #pragma unroll
        for (int i = 0; i < 4; ++i) {
            const int rA = wr + i * 16 + frow;
            const int offA = (rA * 64 + kb) ^ (((rA ^ (rA >> 2)) & 3) << 4);
            af[i] = *(const bf16x8*)((const char*)&lds[cur][0][0] + offA);
            const int rB = wc + i * 16 + frow;
            const int offB = (rB * 64 + kb) ^ (((rB ^ (rB >> 2)) & 3) << 4);
            bfr[i] = *(const bf16x8*)((const char*)&lds[cur][1][0] + offB);
        }
        #pragma unroll
        for (int i = 0; i < 4; ++i)
            #pragma unroll
            for (int j = 0; j < 4; ++j)
                acc[i][j] = __builtin_amdgcn_mfma_f32_16x16x32_bf16(af[i], bfr[j], acc[i][j], 0, 0, 0);
    }

    const int r4 = (ln >> 4) * 4;
    #pragma unroll
    for (int i = 0; i < 4; ++i) {
        #pragma unroll
        for (int j = 0; j < 4; ++j) {
            const int col = bn + wc + j * 16 + frow;
            const float bs = bias[col];
            #pragma unroll
            for (int r = 0; r < 4; ++r) {
                const int row = bm + wr + i * 16 + r4 + r;
                const float v = acc[i][j][r] + bs;
                if (OUT_BF16) ((uint16_t*)Cout)[(size_t)row * N + col] = f2bf(v);
                else          ((float*)Cout)[(size_t)row * N + col]    = v;
            }
        }
    }
}

// ============================================================
// Fused QKV-GEMM + bias + RoPE + windowed attention + un-permute/roll.
// Block = (window b_, half hb: 4 heads), 256 threads = 4 waves.
// LDS: R0 [64][264] u16 (A-tile -> q/k -> P -> O), 33792 B
//      R1 [384][32] u16 (W slice -> VT[4][32][72]),  24576 B
// ============================================================
__global__ __launch_bounds__(256, 2)
void fused_qkv_attn(const float* __restrict__ x, const uint16_t* __restrict__ Wb,
                    const float* __restrict__ biasb, uint16_t* __restrict__ out2)
{
    __shared__ __align__(16) uint16_t lds[29184];
    uint16_t* R0 = lds;            // 16896 elems
    uint16_t* R1 = lds + 16896;    // 12288 elems

    const int tid = threadIdx.x;
    const int wv = tid >> 6, ln = tid & 63;
    const int frow = ln & 15, hi4 = ln >> 4;
    const int fk = hi4 * 8, r4 = hi4 * 4;

    // XCD swizzle keeping the (hb=0, hb=1) pair of a window on one XCD
    const int nb = gridDim.x;                       // 4608
    const int sw = (blockIdx.x & 7) * (nb >> 3) + (blockIdx.x >> 3);
    const int b_ = sw >> 1, hb = sw & 1;

    // ---- Phase 0: stage A-tile (fp32->bf16) and W slice 0 ----
    const float4* xs = (const float4*)(x + (size_t)b_ * 64 * 256);
    const uint16_t* Wblk = Wb + (size_t)hb * 8 * 12288;

    uint4 wr[6];
    #pragma unroll
    for (int it = 0; it < 6; ++it)
        wr[it] = *(const uint4*)(Wblk + (it * 256 + tid) * 8);

    #pragma unroll
    for (int it = 0; it < 8; ++it) {
        const int idx8 = it * 256 + tid;
        float4 a = xs[idx8 * 2], b = xs[idx8 * 2 + 1];
        uint4 o;
        o.x = pack2(a.x, a.y); o.y = pack2(a.z, a.w);
        o.z = pack2(b.x, b.y); o.w = pack2(b.z, b.w);
        *(uint4*)&R0[(idx8 >> 5) * 264 + (idx8 & 31) * 8] = o;
    }
    #pragma unroll
    for (int it = 0; it < 6; ++it)
        *(uint4*)&R1[(it * 256 + tid) * 8] = wr[it];
    __syncthreads();

    // ---- Phase 1: GEMM 64x384, K=256 (wave: 64x96 slice) ----
    f32x4 acc[4][6] = {};
    for (int t = 0; t < 8; ++t) {
        if (t < 7) {
            const uint16_t* Ws = Wblk + (size_t)(t + 1) * 12288;
            #pragma unroll
            for (int it = 0; it < 6; ++it)
                wr[it] = *(const uint4*)(Ws + (it * 256 + tid) * 8);
        }
        bf16x8 af[4], bfr[6];
        #pragma unroll
        for (int i = 0; i < 4; ++i)
            af[i] = *(const bf16x8*)&R0[(16 * i + frow) * 264 + t * 32 + fk];
        #pragma unroll
        for (int j = 0; j < 6; ++j)
            bfr[j] = *(const bf16x8*)&R1[(wv * 96 + 16 * j + frow) * 32 + fk];
        #pragma unroll
        for (int i = 0; i < 4; ++i)
            #pragma unroll
            for (int j = 0; j < 6; ++j)
                acc[i][j] = __builtin_amdgcn_mfma_f32_16x16x32_bf16(af[i], bfr[j], acc[i][j], 0, 0, 0);
        if (t < 7) {
            __syncthreads();                 // readers of slice t done
            #pragma unroll
            for (int it = 0; it < 6; ++it)
                *(uint4*)&R1[(it * 256 + tid) * 8] = wr[it];
            __syncthreads();                 // slice t+1 visible
        }
    }
    __syncthreads();   // all frag reads done; R0/R1 reusable

    // ---- Phase 2: epilogue — bias + RoPE (shfl pairs) -> q/k in R0, V^T in R1
    const float SCALE = 0.17677669529663687f;
    const float invf = __expf(-1.1512925464970231f * (float)(frow & 7));
    const float sgn = (frow & 8) ? 1.f : -1.f;

    #pragma unroll
    for (int j = 0; j < 6; ++j) {
        const int g = wv * 6 + j;          // 0..23 global frag id; col = g*16+frow
        const float bs = biasb[hb * 384 + g * 16 + frow];
        if (g < 16) {                      // q (g<8) or k: apply RoPE
            const int half = g & 1;        // 0: H-rot (pos=wh), 1: W-rot (pos=ww)
            #pragma unroll
            for (int i = 0; i < 4; ++i) {
                #pragma unroll
                for (int r = 0; r < 4; ++r) {
                    const int row = 16 * i + r4 + r;
                    const int pos = half ? (row & 7) : (row >> 3);
                    float sv, cv;
                    __sincosf((float)pos * invf, &sv, &cv);
                    float v = acc[i][j][r] + bs;
                    float part = __shfl_xor(v, 8);
                    float nv = v * cv + sgn * part * sv;
                    if (g < 8) nv *= SCALE;
                    float pp = __shfl_xor(nv, 1);
                    if (!(frow & 1))
                        *(uint32_t*)&R0[row * 264 + g * 16 + frow] = pack2(nv, pp);
                }
            }
        } else {                           // v: no rope, scatter transposed
            const int vh = (g - 16) >> 1;
            const int d = (g & 1) * 16 + frow;
            #pragma unroll
            for (int i = 0; i < 4; ++i)
                #pragma unroll
                for (int r = 0; r < 4; ++r) {
                    const int row = 16 * i + r4 + r;
                    R1[vh * 2304 + d * 72 + row] = f2bf(acc[i][j][r] + bs);
                }
        }
    }
    __syncthreads();

    // ---- Phase 3: attention; wave wv owns head hd = wv ----
    bf16x8 qf[4], kf[4];
    #pragma unroll
    for (int i = 0; i < 4; ++i) {
        qf[i] = *(const bf16x8*)&R0[(16 * i + frow) * 264 + wv * 32 + fk];
        kf[i] = *(const bf16x8*)&R0[(16 * i + frow) * 264 + 128 + wv * 32 + fk];
    }
    f32x4 s[4][4] = {};
    #pragma unroll
    for (int i = 0; i < 4; ++i)
        #pragma unroll
        for (int j = 0; j < 4; ++j)
            s[i][j] = __builtin_amdgcn_mfma_f32_16x16x32_bf16(qf[i], kf[j], s[i][j], 0, 0, 0);

    float p[4][4][4];
    #pragma unroll
    for (int i = 0; i < 4; ++i)
        #pragma unroll
        for (int j = 0; j < 4; ++j)
            #pragma unroll
            for (int r = 0; r < 4; ++r)
                p[i][j][r] = __expf(s[i][j][r]);

    const int wm = b_ % 576;
    if (wm >= 528) {
        int kcls[4];
        #pragma unroll
        for (int j = 0; j < 4; ++j) {
            const int kh = (16 * j + frow) >> 3;
            kcls[j] = (kh < 4) ? 0 : ((kh < 6) ? 1 : 2);
        }
        #pragma unroll
        for (int i = 0; i < 4; ++i)
            #pragma unroll
            for (int r = 0; r < 4; ++r) {
                const int qh = (16 * i + r4 + r) >> 3;
                const int qc = (qh < 4) ? 0 : ((qh < 6) ? 1 : 2);
                #pragma unroll
                for (int j = 0; j < 4; ++j)
                    if (kcls[j] != qc) p[i][j][r] = 0.f;
            }
    }

    float rinv[4][4];
    #pragma unroll
    for (int i = 0; i < 4; ++i)
        #pragma unroll
        for (int r = 0; r < 4; ++r) {
            float sum = p[i][0][r] + p[i][1][r] + p[i][2][r] + p[i][3][r];
            sum += __shfl_xor(sum, 1);
            sum += __shfl_xor(sum, 2);
            sum += __shfl_xor(sum, 4);
            sum += __shfl_xor(sum, 8);
            rinv[i][r] = 1.f / sum;
        }

    __syncthreads();   // everyone's q/k frag reads done -> P may overwrite
    #pragma unroll
    for (int i = 0; i < 4; ++i)
        #pragma unroll
        for (int r = 0; r < 4; ++r) {
            const float sc = rinv[i][r];
            const int row = 16 * i + r4 + r;
            #pragma unroll
            for (int j = 0; j < 4; ++j) {
                float pv = p[i][j][r] * sc;
                float pp = __shfl_xor(pv, 1);
                if (!(frow & 1))
                    *(uint32_t*)&R0[row * 264 + wv * 64 + 16 * j + frow] = pack2(pv, pp);
            }
        }
    __syncthreads();

    bf16x8 pf[4][2], vf[2][2];
    #pragma unroll
    for (int i = 0; i < 4; ++i)
        #pragma unroll
        for (int kc = 0; kc < 2; ++kc)
            pf[i][kc] = *(const bf16x8*)&R0[(16 * i + frow) * 264 + wv * 64 + kc * 32 + fk];
    #pragma unroll
    for (int jv = 0; jv < 2; ++jv)
        #pragma unroll
        for (int kc = 0; kc < 2; ++kc)
            vf[jv][kc] = *(const bf16x8*)&R1[wv * 2304 + (16 * jv + frow) * 72 + kc * 32 + fk];
    __syncthreads();   // all P/V frag reads done -> O may overwrite

    f32x4 o[4][2] = {};
    #pragma unroll
    for (int i = 0; i < 4; ++i)
        #pragma unroll
        for (int jv = 0; jv < 2; ++jv) {
            o[i][jv] = __builtin_amdgcn_mfma_f32_16x16x32_bf16(pf[i][0], vf[jv][0], o[i][jv], 0, 0, 0);
            o[i][jv] = __builtin_amdgcn_mfma_f32_16x16x32_bf16(pf[i][1], vf[jv][1], o[i][jv], 0, 0, 0);
        }

    #pragma unroll
    for (int i = 0; i < 4; ++i)
        #pragma unroll
        for (int jv = 0; jv < 2; ++jv)
            #pragma unroll
            for (int r = 0; r < 4; ++r) {
                float val = o[i][jv][r];
                float pp = __shfl_xor(val, 1);
                if (!(frow & 1))
                    *(uint32_t*)&R0[wv * 2560 + (16 * i + r4 + r) * 40 + 16 * jv + frow] = pack2(val, pp);
            }
    __syncthreads();

    // ---- store: fused un-permute + roll ----
    const int n = ln;
    const int wh = n >> 3, wwp = n & 7;
    const int bw = b_ >> 2, dsw = b_ & 3, dh = dsw >> 1, dw = dsw & 1;
    const int bimg = bw / 144;
    const int t144 = bw % 144;
    const int bh = t144 / 12, bwc = t144 % 12;
    int hp = bh * 16 + wh * 2 + dh + 4;  if (hp >= 192) hp -= 192;
    int wp = bwc * 16 + wwp * 2 + dw + 4; if (wp >= 192) wp -= 192;

    uint16_t* dst = out2 + ((size_t)(bimg * 192 + hp) * 192 + wp) * 256 + (hb * 4 + wv) * 32;
    #pragma unroll
    for (int i = 0; i < 4; ++i)
        *(uint4*)(dst + i * 8) = *(const uint4*)&R0[wv * 2560 + n * 40 + i * 8];
}

// ============================================================
extern "C" void kernel_launch(void* const* d_in, const int* in_sizes, int n_in,
                              void* d_out, int out_size, void* d_ws, size_t ws_size,
                              hipStream_t stream)
{
    const float* x      = (const float*)d_in[0];
    const float* W_qkv  = (const float*)d_in[1];
    const float* b_qkv  = (const float*)d_in[2];
    const float* W_proj = (const float*)d_in[3];
    const float* b_proj = (const float*)d_in[4];
    float* out = (float*)d_out;

    uint16_t* bufb  = (uint16_t*)d_ws;                       // 147456*256
    uint16_t* wtp   = bufb + (size_t)MROWS * KDIM;           // 256*256
    uint16_t* Wb    = wtp + 256 * 256;                       // 196608
    float*    biasb = (float*)(Wb + 196608);                 // 768 f32

    build_wb<<<768, 256, 0, stream>>>(W_qkv, Wb);
    build_biasb<<<3, 256, 0, stream>>>(b_qkv, biasb);
    transpose_cvt_k<<<(KDIM * KDIM + 255) / 256, 256, 0, stream>>>(W_proj, wtp, KDIM, KDIM);

    fused_qkv_attn<<<4608, 256, 0, stream>>>(x, Wb, biasb, bufb);

    gemm_bf16<0><<<(MROWS / 128) * (KDIM / 128), 256, 0, stream>>>(
        bufb, wtp, b_proj, out, MROWS, KDIM, KDIM, KDIM / 128);
}

// Round 5
// 322.024 us; speedup vs baseline: 1.4245x; 1.4245x over previous
//
#include <hip/hip_runtime.h>
#include <hip/hip_bf16.h>
#include <cstdint>

static constexpr int MROWS = 147456;
static constexpr int KDIM  = 256;
static constexpr int QKVN  = 768;

typedef __bf16 bf16x8 __attribute__((ext_vector_type(8)));
typedef float  f32x4  __attribute__((ext_vector_type(4)));

static __device__ __forceinline__ uint16_t f2bf(float f) {
    uint32_t x = __float_as_uint(f);
    x += 0x7FFFu + ((x >> 16) & 1u);   // RNE
    return (uint16_t)(x >> 16);
}
static __device__ __forceinline__ uint32_t pack2(float a, float b) {
    return (uint32_t)f2bf(a) | ((uint32_t)f2bf(b) << 16);
}

// Wt[n][k] = bf16(W[k][n])
__global__ void transpose_cvt_k(const float* __restrict__ W, uint16_t* __restrict__ Wt, int K, int N)
{
    int id = blockIdx.x * blockDim.x + threadIdx.x;
    if (id >= K * N) return;
    int n = id / K, k = id - n * K;
    Wt[id] = f2bf(W[(size_t)k * N + n]);
}

// ============================================================
// QKV GEMM with fused fp32->bf16 convert + bias + RoPE + scale.
// A = x fp32 [147456][256] (reg-staged cvt), B = Wt bf16 [768][256].
// Tile 128(M) x 256(N), BK=32, 8 waves. N-tile == section (q/k/v).
// Output layout qkv2: per (win,head) 12KB block:
//   Q[64 tok][32 d] chunk-swizzled | K same | VT[32 d][64 tok] chunk-swizzled
// Swizzles: q/k chunk c(of 4) at slot c ^ ((tok ^ tok>>2)&3)
//           vt chunk c(of 8) at slot c ^ (d&7)
// ============================================================
__global__ __launch_bounds__(512)
void qkv_gemm(const float* __restrict__ x, const uint16_t* __restrict__ Wt,
              const float* __restrict__ bias, uint16_t* __restrict__ qkv2)
{
    __shared__ __align__(16) uint16_t Abuf[2][4096];
    __shared__ __align__(16) uint16_t Bbuf[2][8192];

    const int tid = threadIdx.x;
    const int wv = tid >> 6, ln = tid & 63;
    const int frow = ln & 15, hi4 = ln >> 4;
    const int r4 = hi4 * 4;

    const int nwg = gridDim.x;                       // 3456
    const int sw = (blockIdx.x & 7) * (nwg >> 3) + (blockIdx.x >> 3);
    const int bm = (sw / 3) * 128;
    const int tn = sw % 3;                           // section: 0=q 1=k 2=v
    const int bn = tn * 256;

    const int wr = (wv >> 2) * 64;                   // 0 / 64
    const int wc = (wv & 3) * 64;                    // 0..192

    // A staging map: thread -> (row 0..127, k-chunk 0..3 of 8 fp32)
    const int arow = tid >> 2;
    const int akq  = tid & 3;
    const int aswz = (arow ^ (arow >> 2)) & 3;
    const float* axp = x + (size_t)(bm + arow) * 256 + akq * 8;

    float4 a0, a1;
    auto loadA = [&](int k0) {
        a0 = *(const float4*)(axp + k0);
        a1 = *(const float4*)(axp + k0 + 4);
    };
    auto writeA = [&](int buf) {
        uint4 o;
        o.x = pack2(a0.x, a0.y); o.y = pack2(a0.z, a0.w);
        o.z = pack2(a1.x, a1.y); o.w = pack2(a1.z, a1.w);
        *(uint4*)&Abuf[buf][arow * 32 + ((akq ^ aswz) * 8)] = o;
    };
    auto stageB = [&](int buf, int k0) {
        #pragma unroll
        for (int it = 0; it < 2; ++it) {
            const int c = it * 512 + tid;
            const int row = c >> 2, kl = c & 3;
            const int ks = kl ^ ((row ^ (row >> 2)) & 3);
            const uint16_t* src = Wt + (size_t)(bn + row) * 256 + k0 + ks * 8;
            uint16_t* d = &Bbuf[buf][(size_t)(it * 512 + wv * 64) * 8];
            __builtin_amdgcn_global_load_lds((const __attribute__((address_space(1))) void*)src,
                                             (__attribute__((address_space(3))) void*)d, 16, 0, 0);
        }
    };

    f32x4 acc[4][4] = {};

    loadA(0);
    stageB(0, 0);
    writeA(0);
    __syncthreads();

    for (int t = 0; t < 8; ++t) {
        const int cur = t & 1;
        if (t < 7) { loadA((t + 1) * 32); stageB(cur ^ 1, (t + 1) * 32); }
        bf16x8 af[4], bf[4];
        #pragma unroll
        for (int i = 0; i < 4; ++i) {
            const int rA = wr + 16 * i + frow;
            af[i] = *(const bf16x8*)&Abuf[cur][rA * 32 + ((hi4 ^ ((rA ^ (rA >> 2)) & 3)) * 8)];
            const int rB = wc + 16 * i + frow;
            bf[i] = *(const bf16x8*)&Bbuf[cur][rB * 32 + ((hi4 ^ ((rB ^ (rB >> 2)) & 3)) * 8)];
        }
        #pragma unroll
        for (int i = 0; i < 4; ++i)
            #pragma unroll
            for (int j = 0; j < 4; ++j)
                acc[i][j] = __builtin_amdgcn_mfma_f32_16x16x32_bf16(af[i], bf[j], acc[i][j], 0, 0, 0);
        if (t < 7) writeA(cur ^ 1);
        __syncthreads();
    }

    // ---- epilogue: bias (+ RoPE + scale for q/k), store head-blocked swizzled ----
    const int win = (bm >> 6) + (wv >> 2);
    const float SCALE = 0.17677669529663687f;

    if (tn < 2) {
        const float invf = __expf(-1.1512925464970231f * (float)(frow & 7));
        const float sgn = (frow & 8) ? 1.f : -1.f;
        const int b0  = (ln >> 5) & 1;     // (r4+r)>=8
        const int a0i = (ln >> 4) & 1;     // (r4)&4 bit
        float cH[4], sH[4], cW[4], sW[4];
        #pragma unroll
        for (int i = 0; i < 4; ++i) __sincosf((float)(2 * i + b0) * invf, &sH[i], &cH[i]);
        #pragma unroll
        for (int r = 0; r < 4; ++r) __sincosf((float)(4 * a0i + r) * invf, &sW[r], &cW[r]);

        #pragma unroll
        for (int j = 0; j < 4; ++j) {
            const int cs = wc + 16 * j + frow;       // col within section
            const int head = cs >> 5;
            const int d = cs & 31;
            const float bs = bias[tn * 256 + cs];
            const size_t base = ((size_t)(win * 8 + head) * 3 + tn) * 2048;
            #pragma unroll
            for (int i = 0; i < 4; ++i) {
                #pragma unroll
                for (int r = 0; r < 4; ++r) {
                    float val = acc[i][j][r] + bs;
                    float part = __shfl_xor(val, 8);
                    float cv, sv;
                    if (j & 1) { cv = cW[r]; sv = sW[r]; }   // W-rot (d>=16)
                    else       { cv = cH[i]; sv = sH[i]; }   // H-rot (d<16)
                    float nv = val * cv + sgn * part * sv;
                    if (tn == 0) nv *= SCALE;
                    const int token = 16 * i + r4 + r;
                    const int sz2 = (token ^ (token >> 2)) & 3;
                    qkv2[base + token * 32 + (((d >> 3) ^ sz2) * 8) + (d & 7)] = f2bf(nv);
                }
            }
        }
    } else {
        #pragma unroll
        for (int j = 0; j < 4; ++j) {
            const int cs = wc + 16 * j + frow;
            const int head = cs >> 5, d = cs & 31;
            const float bs = bias[512 + cs];
            const size_t base = ((size_t)(win * 8 + head) * 3 + 2) * 2048;
            #pragma unroll
            for (int i = 0; i < 4; ++i)
                #pragma unroll
                for (int r = 0; r < 4; ++r) {
                    const int token = 16 * i + r4 + r;
                    qkv2[base + d * 64 + (((token >> 3) ^ (d & 7)) * 8) + (token & 7)]
                        = f2bf(acc[i][j][r] + bs);
                }
        }
    }
}

// ============================================================
// Lean MFMA attention: one wave per (window, head).
// Input per block: contiguous 12KB {Q,K,VT} already roped/scaled/swizzled.
// LDS 12288B: Q@0 K@2048 VT@4096 (u16 elems); P[64][64]@0 overlays Q+K;
// O[64][40]@0 overlays P.
// ============================================================
__global__ __launch_bounds__(64)
void attn_lean(const uint16_t* __restrict__ qkv2, uint16_t* __restrict__ out2)
{
    __shared__ __align__(16) uint16_t lds[6144];

    const int bid = blockIdx.x;
    const int b_ = bid >> 3, head = bid & 7;
    const int ln = threadIdx.x;
    const int frow = ln & 15, hi4 = ln >> 4, r4 = hi4 * 4;

    const uint16_t* src = qkv2 + (size_t)(b_ * 8 + head) * 6144;
    #pragma unroll
    for (int it = 0; it < 12; ++it) {
        __builtin_amdgcn_global_load_lds(
            (const __attribute__((address_space(1))) void*)(src + it * 512 + ln * 8),
            (__attribute__((address_space(3))) void*)(&lds[it * 512]), 16, 0, 0);
    }
    __syncthreads();

    // ---- QK^T ----
    bf16x8 qf[4], kf[4];
    #pragma unroll
    for (int i = 0; i < 4; ++i) {
        const int qrow = 16 * i + frow;
        const int off = qrow * 32 + ((hi4 ^ ((qrow ^ (qrow >> 2)) & 3)) * 8);
        qf[i] = *(const bf16x8*)&lds[off];
        kf[i] = *(const bf16x8*)&lds[2048 + off];
    }
    f32x4 s[4][4] = {};
    #pragma unroll
    for (int i = 0; i < 4; ++i)
        #pragma unroll
        for (int j = 0; j < 4; ++j)
            s[i][j] = __builtin_amdgcn_mfma_f32_16x16x32_bf16(qf[i], kf[j], s[i][j], 0, 0, 0);

    // ---- exp (no max-subtract), analytic mask, row-sum ----
    float p[4][4][4];
    #pragma unroll
    for (int i = 0; i < 4; ++i)
        #pragma unroll
        for (int j = 0; j < 4; ++j)
            #pragma unroll
            for (int r = 0; r < 4; ++r)
                p[i][j][r] = __expf(s[i][j][r]);

    const int wm = b_ % 576;
    if (wm >= 528) {
        int kcls[4];
        #pragma unroll
        for (int j = 0; j < 4; ++j) {
            const int kh = (16 * j + frow) >> 3;
            kcls[j] = (kh < 4) ? 0 : ((kh < 6) ? 1 : 2);
        }
        #pragma unroll
        for (int i = 0; i < 4; ++i)
            #pragma unroll
            for (int r = 0; r < 4; ++r) {
                const int qh = (16 * i + r4 + r) >> 3;
                const int qc = (qh < 4) ? 0 : ((qh < 6) ? 1 : 2);
                #pragma unroll
                for (int j = 0; j < 4; ++j)
                    if (kcls[j] != qc) p[i][j][r] = 0.f;
            }
    }

    float rinv[4][4];
    #pragma unroll
    for (int i = 0; i < 4; ++i)
        #pragma unroll
        for (int r = 0; r < 4; ++r) {
            float sum = p[i][0][r] + p[i][1][r] + p[i][2][r] + p[i][3][r];
            sum += __shfl_xor(sum, 1);
            sum += __shfl_xor(sum, 2);
            sum += __shfl_xor(sum, 4);
            sum += __shfl_xor(sum, 8);
            rinv[i][r] = 1.f / sum;
        }

    // ---- P -> LDS [64][64] chunk-swizzled (overlays Q+K) ----
    __syncthreads();
    #pragma unroll
    for (int i = 0; i < 4; ++i)
        #pragma unroll
        for (int r = 0; r < 4; ++r) {
            const int qrow = 16 * i + r4 + r;
            #pragma unroll
            for (int j = 0; j < 4; ++j) {
                float pv = p[i][j][r];
                float pp = __shfl_xor(pv, 1);
                if (!(frow & 1)) {
                    const int c = 2 * j + (frow >> 3);
                    *(uint32_t*)&lds[qrow * 64 + ((c ^ (qrow & 7)) * 8) + (frow & 7)] = pack2(pv, pp);
                }
            }
        }
    __syncthreads();

    // ---- PV ----
    bf16x8 pf[4][2], vf[2][2];
    #pragma unroll
    for (int i = 0; i < 4; ++i)
        #pragma unroll
        for (int kc = 0; kc < 2; ++kc) {
            const int qrow = 16 * i + frow;
            const int ct = kc * 4 + hi4;
            pf[i][kc] = *(const bf16x8*)&lds[qrow * 64 + ((ct ^ (qrow & 7)) * 8)];
        }
    #pragma unroll
    for (int jv = 0; jv < 2; ++jv)
        #pragma unroll
        for (int kc = 0; kc < 2; ++kc) {
            const int vr = 16 * jv + frow;
            const int ct = kc * 4 + hi4;
            vf[jv][kc] = *(const bf16x8*)&lds[4096 + vr * 64 + ((ct ^ (vr & 7)) * 8)];
        }

    f32x4 o[4][2] = {};
    #pragma unroll
    for (int i = 0; i < 4; ++i)
        #pragma unroll
        for (int jv = 0; jv < 2; ++jv) {
            o[i][jv] = __builtin_amdgcn_mfma_f32_16x16x32_bf16(pf[i][0], vf[jv][0], o[i][jv], 0, 0, 0);
            o[i][jv] = __builtin_amdgcn_mfma_f32_16x16x32_bf16(pf[i][1], vf[jv][1], o[i][jv], 0, 0, 0);
        }

    // ---- O (normalized) -> LDS [64][40] ----
    __syncthreads();
    #pragma unroll
    for (int i = 0; i < 4; ++i)
        #pragma unroll
        for (int jv = 0; jv < 2; ++jv)
            #pragma unroll
            for (int r = 0; r < 4; ++r) {
                float val = o[i][jv][r] * rinv[i][r];
                float pp = __shfl_xor(val, 1);
                if (!(frow & 1))
                    *(uint32_t*)&lds[(16 * i + r4 + r) * 40 + 16 * jv + frow] = pack2(val, pp);
            }
    __syncthreads();

    // ---- coalesced store with fused un-permute + roll ----
    const int n = ln;
    const int wh = n >> 3, wwp = n & 7;
    const int bw = b_ >> 2, dsw = b_ & 3, dh = dsw >> 1, dw = dsw & 1;
    const int bimg = bw / 144;
    const int t144 = bw % 144;
    const int bh = t144 / 12, bwc = t144 % 12;
    int hp = bh * 16 + wh * 2 + dh + 4;  if (hp >= 192) hp -= 192;
    int wp = bwc * 16 + wwp * 2 + dw + 4; if (wp >= 192) wp -= 192;

    uint16_t* dst = out2 + ((size_t)(bimg * 192 + hp) * 192 + wp) * 256 + head * 32;
    #pragma unroll
    for (int i = 0; i < 4; ++i)
        *(uint4*)(dst + i * 8) = *(const uint4*)&lds[n * 40 + i * 8];
}

// ============================================================
// bf16 MFMA GEMM (proj): C[M,N] = A[M,K] @ Bt[N,K]^T + bias
// ============================================================
template<int OUT_BF16>
__global__ __launch_bounds__(256)
void gemm_bf16(const uint16_t* __restrict__ A, const uint16_t* __restrict__ Bt,
               const float* __restrict__ bias, void* __restrict__ Cout,
               int M, int N, int K, int ntn)
{
    __shared__ __align__(16) uint16_t lds[2][2][128 * 32];

    const int tid = threadIdx.x;
    const int wv = tid >> 6, ln = tid & 63;

    const int nwg = gridDim.x;
    const int q8 = nwg >> 3;
    const int sw = (blockIdx.x & 7) * q8 + (blockIdx.x >> 3);
    const int bm = (sw / ntn) * 128;
    const int bn = (sw - (sw / ntn) * ntn) * 128;

    const uint16_t* Ab = A + (size_t)bm * K;
    const uint16_t* Bb = Bt + (size_t)bn * K;

    const int wr = (wv >> 1) * 64;
    const int wc = (wv & 1) * 64;
    const int frow = ln & 15;
    const int kb = (ln >> 4) * 16;

    f32x4 acc[4][4] = {};

    auto stage = [&](int buf, int k0) {
        #pragma unroll
        for (int it = 0; it < 2; ++it) {
            const int c = it * 256 + wv * 64 + ln;
            const int row = c >> 2, kl = c & 3;
            const int ks = kl ^ ((row ^ (row >> 2)) & 3);
            const uint16_t* srcA = Ab + row * K + k0 + ks * 8;
            const uint16_t* srcB = Bb + row * K + k0 + ks * 8;
            uint16_t* dA = &lds[buf][0][(size_t)(it * 256 + wv * 64) * 8];
            uint16_t* dB = &lds[buf][1][(size_t)(it * 256 + wv * 64) * 8];
            __builtin_amdgcn_global_load_lds((const __attribute__((address_space(1))) void*)srcA,
                                             (__attribute__((address_space(3))) void*)dA, 16, 0, 0);
            __builtin_amdgcn_global_load_lds((const __attribute__((address_space(1))) void*)srcB,
                                             (__attribute__((address_space(3))) void*)dB, 16, 0, 0);
        }
    };

    stage(0, 0);
    const int nt = K / 32;
    for (int t = 0; t < nt; ++t) {
        const int cur = t & 1;
        __syncthreads();
        if (t + 1 < nt) stage(cur ^ 1, (t + 1) * 32);
        bf16x8 af[4], bfr[4];
        #pragma unroll
        for (int i = 0; i < 4; ++i) {
            const int rA = wr + i * 16 + frow;
            const int offA = (rA * 64 + kb) ^ (((rA ^ (rA >> 2)) & 3) << 4);
            af[i] = *(const bf16x8*)((const char*)&lds[cur][0][0] + offA);
            const int rB = wc + i * 16 + frow;
            const int offB = (rB * 64 + kb) ^ (((rB ^ (rB >> 2)) & 3) << 4);
            bfr[i] = *(const bf16x8*)((const char*)&lds[cur][1][0] + offB);
        }
        #pragma unroll
        for (int i = 0; i < 4; ++i)
            #pragma unroll
            for (int j = 0; j < 4; ++j)
                acc[i][j] = __builtin_amdgcn_mfma_f32_16x16x32_bf16(af[i], bfr[j], acc[i][j], 0, 0, 0);
    }

    const int r4 = (ln >> 4) * 4;
    #pragma unroll
    for (int i = 0; i < 4; ++i) {
        #pragma unroll
        for (int j = 0; j < 4; ++j) {
            const int col = bn + wc + j * 16 + frow;
            const float bs = bias[col];
            #pragma unroll
            for (int r = 0; r < 4; ++r) {
                const int row = bm + wr + i * 16 + r4 + r;
                const float v = acc[i][j][r] + bs;
                if (OUT_BF16) ((uint16_t*)Cout)[(size_t)row * N + col] = f2bf(v);
                else          ((float*)Cout)[(size_t)row * N + col]    = v;
            }
        }
    }
}

// ============================================================
extern "C" void kernel_launch(void* const* d_in, const int* in_sizes, int n_in,
                              void* d_out, int out_size, void* d_ws, size_t ws_size,
                              hipStream_t stream)
{
    const float* x      = (const float*)d_in[0];
    const float* W_qkv  = (const float*)d_in[1];
    const float* b_qkv  = (const float*)d_in[2];
    const float* W_proj = (const float*)d_in[3];
    const float* b_proj = (const float*)d_in[4];
    float* out = (float*)d_out;

    uint16_t* bufb = (uint16_t*)d_ws;                   // 147456*256
    uint16_t* qkv2 = bufb + (size_t)MROWS * KDIM;       // 147456*768
    uint16_t* wtq  = qkv2 + (size_t)MROWS * QKVN;       // 768*256
    uint16_t* wtp  = wtq + (size_t)QKVN * KDIM;         // 256*256

    transpose_cvt_k<<<(KDIM * QKVN + 255) / 256, 256, 0, stream>>>(W_qkv, wtq, KDIM, QKVN);
    transpose_cvt_k<<<(KDIM * KDIM + 255) / 256, 256, 0, stream>>>(W_proj, wtp, KDIM, KDIM);

    // QKV GEMM + cvt + bias + RoPE (grid = 1152 M-tiles x 3 sections)
    qkv_gemm<<<(MROWS / 128) * 3, 512, 0, stream>>>(x, wtq, b_qkv, qkv2);

    // lean attention
    attn_lean<<<2304 * 8, 64, 0, stream>>>(qkv2, bufb);

    // projection GEMM (fp32 out)
    gemm_bf16<0><<<(MROWS / 128) * (KDIM / 128), 256, 0, stream>>>(
        bufb, wtp, b_proj, out, MROWS, KDIM, KDIM, KDIM / 128);
}